// Round 6
// baseline (133.762 us; speedup 1.0000x reference)
//
#include <hip/hip_runtime.h>

// Problem constants (from reference)
constexpr int F     = 20;        // fields
constexpr int A     = 4;         // len(ACTION)
constexpr int M     = 4;         // sub-codebooks
constexpr int D     = 64;        // EMBED_DIM (= M * 16)
constexpr int MAXK  = 512;
constexpr int FIELD = 50000;
constexpr int V     = FIELD * F; // 1,000,000
constexpr int B     = 8192;
constexpr int G     = 4;         // (b,f) pairs per thread (MLP batching)

typedef float f32x4 __attribute__((ext_vector_type(4)));

// 16 threads per (b,f); thread t owns output float4 at column t*4
// (m = t>>2, pg = t&3). NO cross-lane shuffles: each thread loads its own
// k-indices kv[g][a] = cb_index[a][xo][m] directly. The 4 lanes of a
// pg-group read the same address (HW broadcast); per (cluster,g,a) the
// 16 lanes touch one 16B segment — same DRAM lines as the cooperative
// scheme, but 16 independent kv->codebook chains per thread.
__global__ __launch_bounds__(256)
void wsqe_kernel(const int* __restrict__ x,
                 const float* __restrict__ arch_prob,
                 const float* __restrict__ codebooks,
                 const int* __restrict__ cb_index,
                 float* __restrict__ out) {
    const int gid     = blockIdx.x * 256 + threadIdx.x;
    const int t       = gid & 15;          // sub-lane within cluster
    const int cluster = gid >> 4;
    const int bf0     = cluster * G;       // first bf of this thread's batch
    const int m       = t >> 2;            // this thread's sub-codebook

    // ---- batched x load: G consecutive ints, 16B aligned ----
    const int4 xv = *reinterpret_cast<const int4*>(x + bf0);
    const int xs[G] = {xv.x, xv.y, xv.z, xv.w};

    int fs[G];
    {
        int f0 = bf0 % F;
        #pragma unroll
        for (int g = 0; g < G; ++g) {
            fs[g] = f0;
            f0 = (f0 + 1 == F) ? 0 : f0 + 1;
        }
    }

    // ---- issue all G*A independent scattered kv gathers ----
    int kv[G][A];
    #pragma unroll
    for (int g = 0; g < G; ++g) {
        const int xo4 = (xs[g] + fs[g] * FIELD) << 2;
        #pragma unroll
        for (int a = 0; a < A; ++a) {
            kv[g][a] = cb_index[(a * (V * M)) + xo4 + m];
        }
    }

    // ---- codebook float4 loads, each dependent only on its own kv ----
    float4 v[G][A];
    #pragma unroll
    for (int g = 0; g < G; ++g) {
        const float* cbase = codebooks + fs[g] * (MAXK * D) + (t << 2);
        #pragma unroll
        for (int a = 0; a < A; ++a) {
            v[g][a] = *reinterpret_cast<const float4*>(cbase + kv[g][a] * D);
        }
    }

    // ---- weighted sums + nontemporal stores ----
    #pragma unroll
    for (int g = 0; g < G; ++g) {
        const float4 w = *reinterpret_cast<const float4*>(arch_prob + fs[g] * A);
        f32x4 acc;
        acc.x = w.x * v[g][0].x; acc.y = w.x * v[g][0].y;
        acc.z = w.x * v[g][0].z; acc.w = w.x * v[g][0].w;
        acc.x = fmaf(w.y, v[g][1].x, acc.x); acc.y = fmaf(w.y, v[g][1].y, acc.y);
        acc.z = fmaf(w.y, v[g][1].z, acc.z); acc.w = fmaf(w.y, v[g][1].w, acc.w);
        acc.x = fmaf(w.z, v[g][2].x, acc.x); acc.y = fmaf(w.z, v[g][2].y, acc.y);
        acc.z = fmaf(w.z, v[g][2].z, acc.z); acc.w = fmaf(w.z, v[g][2].w, acc.w);
        acc.x = fmaf(w.w, v[g][3].x, acc.x); acc.y = fmaf(w.w, v[g][3].y, acc.y);
        acc.z = fmaf(w.w, v[g][3].z, acc.z); acc.w = fmaf(w.w, v[g][3].w, acc.w);

        f32x4* dst = reinterpret_cast<f32x4*>(out + (size_t)(bf0 + g) * D + (t << 2));
        __builtin_nontemporal_store(acc, dst);
    }
}

extern "C" void kernel_launch(void* const* d_in, const int* in_sizes, int n_in,
                              void* d_out, int out_size, void* d_ws, size_t ws_size,
                              hipStream_t stream) {
    const int*   x         = (const int*)d_in[0];
    const float* arch_prob = (const float*)d_in[1];
    const float* codebooks = (const float*)d_in[2];
    const int*   cb_index  = (const int*)d_in[3];
    float*       out       = (float*)d_out;

    // clusters = B*F/G = 40,960 ; threads = 655,360 ; blocks = 2,560 (exact)
    const int total  = (B * F / G) * 16;
    const int blocks = total / 256;
    wsqe_kernel<<<blocks, 256, 0, stream>>>(x, arch_prob, codebooks, cb_index, out);
}